// Round 6
// baseline (1304.289 us; speedup 1.0000x reference)
//
#include <hip/hip_runtime.h>
#include <stdint.h>

// Problem constants
#define BB     64
#define NPTS   1024
#define DIM    256
#define BOOKN  2048
#define NC     16
#define NROWS  (BB*NPTS)           // 65536
#define HALF_N 67108864u           // NROWS*BOOKN/2
#define HALF_ROWS 32768            // NROWS/2

// d_out layout (floats): [zq | precision_q | logits | mu_mix]
#define OFF_PQ ((size_t)NROWS*DIM)            // 16777216
#define OFF_LG (OFF_PQ + 1)                   // 16777217
#define OFF_MM (OFF_LG + (size_t)NROWS*BOOKN) // 150994945

// ws layout (floats): bn[2048], rn[65536], pq[1], pad, bookF(1MB bf16),
// then tier A: bookQ(1MB bf16)   (tier B instead: wsMax 65536 u32 at WS_MX)
#define WS_RN 2048
#define WS_PQ (2048 + NROWS)
#define WS_BF 67592                            // float offset, 16B aligned
#define WS_MX (WS_BF + (BOOKN*DIM)/2)          // 329736 (tier B wsMax spot)
#define WS_BQ 329736                           // tier A bookQ spot (same offset)
#define WS_FUSED_BYTES ((size_t)(WS_MX + NROWS) * 4)        // 1,581,088 (tier B)
#define WS_A_BYTES ((size_t)(WS_BQ + (BOOKN*DIM)/2) * 4)    // 2,367,520 (tier A)

// fast hardware transcendentals (v_log_f32 = log2, v_exp_f32 = exp2), with
// guaranteed-compile libm fallback. NOTE: __log2f/__exp2f collide with glibc.
#if defined(__has_builtin)
# if __has_builtin(__builtin_amdgcn_logf)
#  define FAST_LOG2(x) __builtin_amdgcn_logf(x)
# endif
# if __has_builtin(__builtin_amdgcn_exp2f)
#  define FAST_EXP2(x) __builtin_amdgcn_exp2f(x)
# endif
#endif
#ifndef FAST_LOG2
# define FAST_LOG2(x) log2f(x)
#endif
#ifndef FAST_EXP2
# define FAST_EXP2(x) exp2f(x)
#endif

typedef unsigned short u16;
typedef short s8v  __attribute__((ext_vector_type(8)));   // 8 bf16 (MFMA A/B frag)
typedef float f32x4 __attribute__((ext_vector_type(4)));  // MFMA C/D frag
typedef u16  u16x4 __attribute__((ext_vector_type(4)));
typedef u16  u16x8 __attribute__((ext_vector_type(8)));

__device__ __forceinline__ u16 f2bf(float x){
  uint32_t u = __float_as_uint(x);
  return (u16)((u + 0x7fffu + ((u >> 16) & 1u)) >> 16);   // RNE
}
__device__ __forceinline__ float bf2f(u16 b){
  return __uint_as_float(((uint32_t)b) << 16);
}

// monotone float<->uint map for atomicMax (tier B only)
__device__ __forceinline__ uint32_t mf_map(float f){
  uint32_t b = __float_as_uint(f);
  return (b & 0x80000000u) ? ~b : (b | 0x80000000u);
}
__device__ __forceinline__ float mf_unmap(uint32_t u){
  uint32_t b = (u & 0x80000000u) ? (u ^ 0x80000000u) : ~u;
  return __uint_as_float(b);
}

// ---------------- threefry2x32-20, JAX semantics, key = (0, 42) -------------
__device__ __forceinline__ uint32_t rotl32(uint32_t x, int r){
  return (x << r) | (x >> (32 - r));
}

__device__ __forceinline__ void threefry_0_42(uint32_t x0, uint32_t x1,
                                              uint32_t& o0, uint32_t& o1){
  const uint32_t ks0 = 0u;
  const uint32_t ks1 = 42u;
  const uint32_t ks2 = 0u ^ 42u ^ 0x1BD11BDAu;
  x0 += ks0; x1 += ks1;
#define TF_R(r) { x0 += x1; x1 = rotl32(x1, r); x1 ^= x0; }
  TF_R(13) TF_R(15) TF_R(26) TF_R(6)
  x0 += ks1; x1 += ks2 + 1u;
  TF_R(17) TF_R(29) TF_R(16) TF_R(24)
  x0 += ks2; x1 += ks0 + 2u;
  TF_R(13) TF_R(15) TF_R(26) TF_R(6)
  x0 += ks0; x1 += ks1 + 3u;
  TF_R(17) TF_R(29) TF_R(16) TF_R(24)
  x0 += ks1; x1 += ks2 + 4u;
  TF_R(13) TF_R(15) TF_R(26) TF_R(6)
  x0 += ks2; x1 += ks0 + 5u;
#undef TF_R
  o0 = x0; o1 = x1;
}

// ---------------- K0: book norms + precision_q + (tier B) rowmax init -------
__global__ __launch_bounds__(256) void k_prep(const float* __restrict__ book,
    const float* __restrict__ lpq, float* __restrict__ bn,
    float* __restrict__ ws_pq, float* __restrict__ pq_out,
    unsigned int* __restrict__ wsMax)
{
  __shared__ float red[4];
  const int j = blockIdx.x, t = threadIdx.x;
  const int gid = j*256 + t;
  if (wsMax != nullptr && gid < NROWS) wsMax[gid] = 0u;
  float v = book[(size_t)j*DIM + t];
  float s = v*v;
  #pragma unroll
  for (int o = 32; o; o >>= 1) s += __shfl_down(s, o, 64);
  const int wv = t >> 6, ln = t & 63;
  if (ln == 0) red[wv] = s;
  __syncthreads();
  if (t == 0){
    bn[j] = red[0] + red[1] + red[2] + red[3];
    if (j == 0){
      float pq = fmaxf(expf(lpq[0]), 1e-10f);
      float prec = 0.5f / pq;
      ws_pq[0] = prec;
      pq_out[0] = prec;
    }
  }
}

// ---------------- K0b: bf16 book in up to three layouts ---------------------
// bookF (PV frag order): e = book[jc*32 + (l>>4)*8 + e][dt*16 + (l&15)]
// bookR (row-major bf16, tier B k_logits staging)
// bookQ (QK^T frag order): frag (jt,ks,l): e = book[jt*16+(l&15)][ks*32+(l>>4)*8+e]
__global__ __launch_bounds__(256) void k_bookf(const float* __restrict__ book,
    u16* __restrict__ bookF, u16* __restrict__ bookR, u16* __restrict__ bookQ)
{
  const int tid = blockIdx.x*256 + threadIdx.x;   // 0..65535
  {
    const int l  = tid & 63;
    const int dt = (tid >> 6) & 15;
    const int jc = tid >> 10;
    const int d  = dt*16 + (l & 15);
    const int jb = jc*32 + (l >> 4)*8;
    u16x8 v;
    #pragma unroll
    for (int e = 0; e < 8; ++e) v[e] = f2bf(book[(size_t)(jb + e)*DIM + d]);
    *(u16x8*)&bookF[(size_t)tid*8] = v;
  }
  if (bookR != nullptr){
    const int rr = tid >> 5;
    const int cc = (tid & 31) * 8;
    const float4 f0 = *(const float4*)&book[(size_t)rr*DIM + cc];
    const float4 f1 = *(const float4*)&book[(size_t)rr*DIM + cc + 4];
    u16x8 wv;
    wv[0] = f2bf(f0.x); wv[1] = f2bf(f0.y); wv[2] = f2bf(f0.z); wv[3] = f2bf(f0.w);
    wv[4] = f2bf(f1.x); wv[5] = f2bf(f1.y); wv[6] = f2bf(f1.z); wv[7] = f2bf(f1.w);
    *(u16x8*)&bookR[(size_t)rr*DIM + cc] = wv;
  }
  if (bookQ != nullptr){
    const int l  = tid & 63;
    const int ks = (tid >> 6) & 7;
    const int jt = tid >> 9;                 // 0..127
    const int row = jt*16 + (l & 15);
    const int d0  = ks*32 + (l >> 4)*8;
    const float4 f0 = *(const float4*)&book[(size_t)row*DIM + d0];
    const float4 f1 = *(const float4*)&book[(size_t)row*DIM + d0 + 4];
    u16x8 v;
    v[0] = f2bf(f0.x); v[1] = f2bf(f0.y); v[2] = f2bf(f0.z); v[3] = f2bf(f0.w);
    v[4] = f2bf(f1.x); v[5] = f2bf(f1.y); v[6] = f2bf(f1.z); v[7] = f2bf(f1.w);
    *(u16x8*)&bookQ[(size_t)tid*8] = v;
  }
}

// ---------------- K1: mu_mix, row norms, optional zpBF ----------------------
__global__ __launch_bounds__(256) void k_mix(const float* __restrict__ z,
    const float* __restrict__ cp, const float* __restrict__ mu,
    u16* __restrict__ zpBF, float* __restrict__ mm, float* __restrict__ rn)
{
  __shared__ float s_cp[BB*NC];
  const int n  = blockIdx.x;
  const int t  = threadIdx.x;
  const int wv = t >> 6, ln = t & 63;
  for (int e = t; e < BB*NC; e += 256) s_cp[e] = cp[e];
  const int d0 = ln*4;
  float4 muv[NC];
  #pragma unroll
  for (int c = 0; c < NC; ++c)
    muv[c] = *(const float4*)&mu[(size_t)(c*NPTS + n)*DIM + d0];
  __syncthreads();
  const int b0 = blockIdx.y*32 + wv*8;
  #pragma unroll 2
  for (int bb = 0; bb < 8; ++bb){
    const int b = b0 + bb;
    const size_t idx = ((size_t)(b*NPTS + n))*DIM + d0;
    const float4 z4 = *(const float4*)&z[idx];
    float4 m4 = {0.f, 0.f, 0.f, 0.f};
    #pragma unroll
    for (int c = 0; c < NC; ++c){
      const float wgt = s_cp[b*NC + c];
      m4.x = fmaf(wgt, muv[c].x, m4.x);
      m4.y = fmaf(wgt, muv[c].y, m4.y);
      m4.z = fmaf(wgt, muv[c].z, m4.z);
      m4.w = fmaf(wgt, muv[c].w, m4.w);
    }
    float4 zp4;
    zp4.x = z4.x + m4.x; zp4.y = z4.y + m4.y;
    zp4.z = z4.z + m4.z; zp4.w = z4.w + m4.w;
    *(float4*)&mm[idx] = m4;
    if (zpBF != nullptr){
      u16x4 zb;
      zb[0] = f2bf(zp4.x); zb[1] = f2bf(zp4.y);
      zb[2] = f2bf(zp4.z); zb[3] = f2bf(zp4.w);
      *(u16x4*)&zpBF[idx] = zb;
    }
    float s = zp4.x*zp4.x + zp4.y*zp4.y + zp4.z*zp4.z + zp4.w*zp4.w;
    #pragma unroll
    for (int o = 32; o; o >>= 1) s += __shfl_down(s, o, 64);
    if (ln == 0) rn[b*NPTS + n] = s;
  }
}

// ================= TIER A: single fused logits+softmax+zq kernel ============
// Block = 32 threefry row-pairs (64 rows; s<32 -> i0p+s, s>=32 -> +HALF_ROWS).
// A (zp bf16) held in registers per wave (16 rows). bookQ streamed via dbuf LDS.
// Pass 1: QK^T -> logits write + in-wave row max. Pass 2: recompute QK^T
// (bit-identical) -> sL -> threefry/gumbel -> sP(bf16) -> PV MFMA -> zq.
#define SLP 36
__global__ __launch_bounds__(256) void k_fused(const float* __restrict__ z,
    const float* __restrict__ mm, const float* __restrict__ rn,
    const float* __restrict__ bn, const float* __restrict__ ws_pq,
    const u16* __restrict__ bookQ, const u16* __restrict__ bookF,
    const int* __restrict__ temp, float* __restrict__ logits,
    float* __restrict__ zq)
{
  __shared__ u16 sQ[2][8192];      // dbuf bookQ chunk (16 frags x 64 x 8)
  __shared__ float sL[64*SLP];     // S tile handoff (pass 2)
  __shared__ u16 sP[64*40];        // bf16 P tile
  __shared__ float sM[64];
  __shared__ float sS[64][8];
  __shared__ float sInv[64];

  const int t  = threadIdx.x;
  const int w  = t >> 6;
  const int l  = t & 63;
  const int ll = l & 15, lh = l >> 4;
  const int i0p = blockIdx.x * 32;
  const float pq = ws_pq[0];
  const float tinv = 1.0f / (float)temp[0];
  const float sc = tinv * 1.44269504f;

  // A-frags: wave w owns s-rows [w*16, w*16+16); frag row = w*16 + ll
  const int sArow = w*16 + ll;
  const int giA_r = (sArow < 32) ? (i0p + sArow) : (i0p + sArow - 32 + HALF_ROWS);
  s8v aF[8];
  #pragma unroll
  for (int ks = 0; ks < 8; ++ks){
    const size_t base = (size_t)giA_r*DIM + ks*32 + lh*8;
    const float4 z0 = *(const float4*)&z[base];
    const float4 z1 = *(const float4*)&z[base + 4];
    const float4 m0 = *(const float4*)&mm[base];
    const float4 m1 = *(const float4*)&mm[base + 4];
    s8v v;
    v[0] = f2bf(z0.x + m0.x); v[1] = f2bf(z0.y + m0.y);
    v[2] = f2bf(z0.z + m0.z); v[3] = f2bf(z0.w + m0.w);
    v[4] = f2bf(z1.x + m1.x); v[5] = f2bf(z1.y + m1.y);
    v[6] = f2bf(z1.z + m1.z); v[7] = f2bf(z1.w + m1.w);
    aF[ks] = v;
  }
  // rn + output row ids for this lane's C/D rows (row = lh*4 + r within tile)
  float rnv[4]; int giC[4];
  #pragma unroll
  for (int r = 0; r < 4; ++r){
    const int s = w*16 + lh*4 + r;
    giC[r] = (s < 32) ? (i0p + s) : (i0p + s - 32 + HALF_ROWS);
    rnv[r] = rn[giC[r]];
  }

  // -------- pass 1: logits + in-wave row max --------
  float vmax[4] = {-3.4e38f, -3.4e38f, -3.4e38f, -3.4e38f};
  for (int jc = 0; jc < 64; ++jc){
    u16* q = sQ[jc & 1];
    #pragma unroll
    for (int e = 0; e < 4; ++e){
      const int off = (e*256 + t)*8;
      *(u16x8*)&q[off] = *(const u16x8*)&bookQ[(size_t)jc*8192 + off];
    }
    __syncthreads();
    f32x4 accS[2];
    accS[0] = (f32x4){0.f,0.f,0.f,0.f};
    accS[1] = (f32x4){0.f,0.f,0.f,0.f};
    #pragma unroll
    for (int n = 0; n < 2; ++n)
      #pragma unroll
      for (int ks = 0; ks < 8; ++ks)
        accS[n] = __builtin_amdgcn_mfma_f32_16x16x32_bf16(
            aF[ks], *(const s8v*)&q[((n*8 + ks)*64 + l)*8], accS[n], 0, 0, 0);
    const float bnv[2] = { bn[jc*32 + ll], bn[jc*32 + 16 + ll] };
    #pragma unroll
    for (int n = 0; n < 2; ++n)
      #pragma unroll
      for (int r = 0; r < 4; ++r){
        const float val = -pq * (rnv[r] + bnv[n] - 2.0f*accS[n][r]);
        logits[(size_t)giC[r]*BOOKN + jc*32 + n*16 + ll] = val;
        vmax[r] = fmaxf(vmax[r], val);
      }
  }
  // row max across the 16 lanes sharing each row -> sM (+17 gumbel headroom)
  #pragma unroll
  for (int r = 0; r < 4; ++r){
    float m = vmax[r];
    #pragma unroll
    for (int o = 1; o < 16; o <<= 1) m = fmaxf(m, __shfl_xor(m, o, 64));
    if (ll == 0) sM[w*16 + lh*4 + r] = m + 17.0f;
  }
  __syncthreads();

  // -------- pass 2: recompute S -> softmax sample -> PV --------
  const int srA = t >> 3;
  const int sj0 = (t & 7) * 4;
  const int giA = i0p + srA;
  const float mA = sM[srA];
  const float mB = sM[srA + 32];

  f32x4 acc[4][4];
  #pragma unroll
  for (int m = 0; m < 4; ++m)
    #pragma unroll
    for (int n = 0; n < 4; ++n)
      acc[m][n] = (f32x4){0.f, 0.f, 0.f, 0.f};
  float sumA = 0.f, sumB = 0.f;

  for (int jc = 0; jc < 64; ++jc){
    u16* q = sQ[jc & 1];
    #pragma unroll
    for (int e = 0; e < 4; ++e){
      const int off = (e*256 + t)*8;
      *(u16x8*)&q[off] = *(const u16x8*)&bookQ[(size_t)jc*8192 + off];
    }
    __syncthreads();                                   // b1: sQ ready
    f32x4 accS[2];
    accS[0] = (f32x4){0.f,0.f,0.f,0.f};
    accS[1] = (f32x4){0.f,0.f,0.f,0.f};
    #pragma unroll
    for (int n = 0; n < 2; ++n)
      #pragma unroll
      for (int ks = 0; ks < 8; ++ks)
        accS[n] = __builtin_amdgcn_mfma_f32_16x16x32_bf16(
            aF[ks], *(const s8v*)&q[((n*8 + ks)*64 + l)*8], accS[n], 0, 0, 0);
    const float bnv[2] = { bn[jc*32 + ll], bn[jc*32 + 16 + ll] };
    #pragma unroll
    for (int n = 0; n < 2; ++n)
      #pragma unroll
      for (int r = 0; r < 4; ++r)
        sL[(w*16 + lh*4 + r)*SLP + n*16 + ll] =
            -pq * (rnv[r] + bnv[n] - 2.0f*accS[n][r]);
    __syncthreads();                                   // b2: sL ready

    // threefry/gumbel -> p (bf16) into sP, track sums
    {
      const float4 lA4 = *(const float4*)&sL[srA*SLP + sj0];
      const float4 lB4 = *(const float4*)&sL[(srA + 32)*SLP + sj0];
      const float la[4] = {lA4.x, lA4.y, lA4.z, lA4.w};
      const float lb[4] = {lB4.x, lB4.y, lB4.z, lB4.w};
      const int jbase = jc*32 + sj0;
      #pragma unroll
      for (int e = 0; e < 4; ++e){
        const uint32_t p = (uint32_t)(giA*BOOKN + jbase + e);   // < HALF_N
        uint32_t o0, o1;
        threefry_0_42(p, p + HALF_N, o0, o1);
        const float uA = __uint_as_float((o0 >> 9) | 0x3f800000u) - 1.0f;
        const float uB = __uint_as_float((o1 >> 9) | 0x3f800000u) - 1.0f;
        const float wAv = fmaf(-0.69314718f, FAST_LOG2(uA + 1e-10f), 1e-10f);
        const float wBv = fmaf(-0.69314718f, FAST_LOG2(uB + 1e-10f), 1e-10f);
        const float eAv = ((la[e] - mA) - 0.69314718f*FAST_LOG2(wAv)) * sc;
        const float eBv = ((lb[e] - mB) - 0.69314718f*FAST_LOG2(wBv)) * sc;
        const u16 pa = f2bf(FAST_EXP2(eAv));
        const u16 pb = f2bf(FAST_EXP2(eBv));
        sP[srA*40 + sj0 + e]        = pa;
        sP[(srA + 32)*40 + sj0 + e] = pb;
        sumA += bf2f(pa);
        sumB += bf2f(pb);
      }
    }
    // PV B frags (per-wave distinct d-slice, L2-resident bookF)
    s8v bF[4];
    #pragma unroll
    for (int n = 0; n < 4; ++n)
      bF[n] = *(const s8v*)&bookF[((size_t)(jc*16 + w*4 + n)*64 + l)*8];
    __syncthreads();                                   // b3: sP ready
    s8v aP[4];
    #pragma unroll
    for (int m = 0; m < 4; ++m)
      aP[m] = *(const s8v*)&sP[(m*16 + ll)*40 + lh*8];
    #pragma unroll
    for (int n = 0; n < 4; ++n)
      #pragma unroll
      for (int m = 0; m < 4; ++m)
        acc[m][n] = __builtin_amdgcn_mfma_f32_16x16x32_bf16(aP[m], bF[n], acc[m][n], 0, 0, 0);
  }

  // S reduction (8 partials per row)
  sS[srA][t & 7]      = sumA;
  sS[srA + 32][t & 7] = sumB;
  __syncthreads();
  if (t < 64){
    float s = 0.f;
    #pragma unroll
    for (int e = 0; e < 8; ++e) s += sS[t][e];
    sInv[t] = 1.0f / s;
  }
  __syncthreads();

  // epilogue: zq = acc / S.  C/D: col(d) = lane&15, row = (lane>>4)*4 + reg
  #pragma unroll
  for (int m = 0; m < 4; ++m){
    #pragma unroll
    for (int r = 0; r < 4; ++r){
      const int lr = m*16 + lh*4 + r;
      const int gi = (lr < 32) ? (i0p + lr) : (i0p + lr - 32 + HALF_ROWS);
      const float inv = sInv[lr];
      #pragma unroll
      for (int n = 0; n < 4; ++n)
        zq[(size_t)gi*DIM + w*64 + n*16 + ll] = acc[m][n][r] * inv;
    }
  }
}

// ================= TIER B/C fallback kernels (round-5-proven) ===============
__global__ __launch_bounds__(256) void k_logits(const u16* __restrict__ zpBF,
    const u16* __restrict__ bookR, const float* __restrict__ rn,
    const float* __restrict__ bn, const float* __restrict__ ws_pq,
    float* __restrict__ logits, unsigned int* __restrict__ wsMax)
{
  __shared__ u16 sA[128*72];
  __shared__ u16 sB[128*72];
  const int t  = threadIdx.x;
  const int l  = t & 63;
  const int w  = t >> 6;
  const int i0 = blockIdx.y * 128;
  const int j0 = blockIdx.x * 128;
  const int wr = (w >> 1) * 64;
  const int wc = (w & 1) * 64;
  const int ll = l & 15, lh = l >> 4;

  f32x4 acc[4][4];
  #pragma unroll
  for (int m = 0; m < 4; ++m)
    #pragma unroll
    for (int n = 0; n < 4; ++n)
      acc[m][n] = (f32x4){0.f, 0.f, 0.f, 0.f};

  for (int k0 = 0; k0 < DIM; k0 += 64){
    #pragma unroll
    for (int e = 0; e < 4; ++e){
      const int idx = e*256 + t;
      const int r   = idx >> 3;
      const int c8  = (idx & 7) * 8;
      *(u16x8*)&sA[r*72 + c8] = *(const u16x8*)&zpBF[(size_t)(i0 + r)*DIM + k0 + c8];
      *(u16x8*)&sB[r*72 + c8] = *(const u16x8*)&bookR[(size_t)(j0 + r)*DIM + k0 + c8];
    }
    __syncthreads();
    #pragma unroll
    for (int kk = 0; kk < 2; ++kk){
      s8v aF[4], bF[4];
      #pragma unroll
      for (int m = 0; m < 4; ++m)
        aF[m] = *(const s8v*)&sA[(wr + m*16 + ll)*72 + kk*32 + lh*8];
      #pragma unroll
      for (int n = 0; n < 4; ++n)
        bF[n] = *(const s8v*)&sB[(wc + n*16 + ll)*72 + kk*32 + lh*8];
      #pragma unroll
      for (int m = 0; m < 4; ++m)
        #pragma unroll
        for (int n = 0; n < 4; ++n)
          acc[m][n] = __builtin_amdgcn_mfma_f32_16x16x32_bf16(aF[m], bF[n], acc[m][n], 0, 0, 0);
    }
    __syncthreads();
  }

  const float pq = ws_pq[0];
  float bnv[4];
  #pragma unroll
  for (int n = 0; n < 4; ++n) bnv[n] = bn[j0 + wc + n*16 + ll];
  #pragma unroll
  for (int m = 0; m < 4; ++m){
    #pragma unroll
    for (int r = 0; r < 4; ++r){
      const int i = i0 + wr + m*16 + lh*4 + r;
      const float rni = rn[i];
      const size_t base = (size_t)i*BOOKN + j0 + wc + ll;
      float vmax = -3.4e38f;
      #pragma unroll
      for (int n = 0; n < 4; ++n){
        const float val = -pq * (rni + bnv[n] - 2.0f*acc[m][n][r]);
        logits[base + n*16] = val;
        vmax = fmaxf(vmax, val);
      }
      if (wsMax != nullptr){
        #pragma unroll
        for (int o = 1; o < 16; o <<= 1)
          vmax = fmaxf(vmax, __shfl_xor(vmax, o, 64));
        if (ll == 0) atomicMax(&wsMax[i], mf_map(vmax));
      }
    }
  }
}

__global__ __launch_bounds__(256) void k_zq(const float* __restrict__ logits,
    const u16* __restrict__ bookF, const int* __restrict__ temp,
    const unsigned int* __restrict__ wsMax, float* __restrict__ zq)
{
  __shared__ u16 sP[64*40];
  __shared__ float sM[64];
  __shared__ float sS[64][8];
  __shared__ float sInv[64];
  const int t  = threadIdx.x;
  const int i0 = blockIdx.x * 32;
  const float tinv = 1.0f / (float)temp[0];
  const float sc = tinv * 1.44269504f;

  if (wsMax != nullptr){
    if (t < 64){
      const int gi = (t < 32) ? (i0 + t) : (i0 + t - 32 + HALF_ROWS);
      sM[t] = mf_unmap(wsMax[gi]) + 17.0f;
    }
  } else {
    const int wv = t >> 6, ln = t & 63;
    for (int rr = 0; rr < 16; ++rr){
      const int r = wv*16 + rr;
      const int gi = (r < 32) ? (i0 + r) : (i0 + r - 32 + HALF_ROWS);
      const float* row = logits + (size_t)gi*BOOKN;
      float mx = -3.4e38f;
      #pragma unroll 4
      for (int e = 0; e < 32; ++e) mx = fmaxf(mx, row[e*64 + ln]);
      #pragma unroll
      for (int o = 32; o; o >>= 1) mx = fmaxf(mx, __shfl_down(mx, o, 64));
      if (ln == 0) sM[r] = mx + 17.0f;
    }
  }
  __syncthreads();

  const int w   = t >> 6;
  const int l   = t & 63;
  const int ll  = l & 15, lh = l >> 4;
  const int srA = t >> 3;
  const int sj0 = (t & 7) * 4;
  const int giA = i0 + srA;
  const float mA = sM[srA];
  const float mB = sM[srA + 32];
  const float* rowA = logits + (size_t)giA*BOOKN;
  const float* rowB = logits + (size_t)(giA + HALF_ROWS)*BOOKN;

  f32x4 acc[4][4];
  #pragma unroll
  for (int m = 0; m < 4; ++m)
    #pragma unroll
    for (int n = 0; n < 4; ++n)
      acc[m][n] = (f32x4){0.f, 0.f, 0.f, 0.f};
  float sumA = 0.f, sumB = 0.f;

  for (int jc = 0; jc < 64; ++jc){
    const int jbase = jc*32 + sj0;
    const float4 lA4 = *(const float4*)(rowA + jbase);
    const float4 lB4 = *(const float4*)(rowB + jbase);
    const float la[4] = {lA4.x, lA4.y, lA4.z, lA4.w};
    const float lb[4] = {lB4.x, lB4.y, lB4.z, lB4.w};
    #pragma unroll
    for (int e = 0; e < 4; ++e){
      const uint32_t p = (uint32_t)(giA*BOOKN + jbase + e);
      uint32_t o0, o1;
      threefry_0_42(p, p + HALF_N, o0, o1);
      const float uA = __uint_as_float((o0 >> 9) | 0x3f800000u) - 1.0f;
      const float uB = __uint_as_float((o1 >> 9) | 0x3f800000u) - 1.0f;
      const float wAv = fmaf(-0.69314718f, FAST_LOG2(uA + 1e-10f), 1e-10f);
      const float wBv = fmaf(-0.69314718f, FAST_LOG2(uB + 1e-10f), 1e-10f);
      const float eAv = ((la[e] - mA) - 0.69314718f*FAST_LOG2(wAv)) * sc;
      const float eBv = ((lb[e] - mB) - 0.69314718f*FAST_LOG2(wBv)) * sc;
      const u16 pa = f2bf(FAST_EXP2(eAv));
      const u16 pb = f2bf(FAST_EXP2(eBv));
      sP[srA*40 + sj0 + e]        = pa;
      sP[(srA + 32)*40 + sj0 + e] = pb;
      sumA += bf2f(pa);
      sumB += bf2f(pb);
    }
    s8v bF[4];
    #pragma unroll
    for (int n = 0; n < 4; ++n)
      bF[n] = *(const s8v*)&bookF[((size_t)(jc*16 + w*4 + n)*64 + l)*8];
    __syncthreads();
    s8v aF[4];
    #pragma unroll
    for (int m = 0; m < 4; ++m)
      aF[m] = *(const s8v*)&sP[(m*16 + ll)*40 + lh*8];
    #pragma unroll
    for (int n = 0; n < 4; ++n)
      #pragma unroll
      for (int m = 0; m < 4; ++m)
        acc[m][n] = __builtin_amdgcn_mfma_f32_16x16x32_bf16(aF[m], bF[n], acc[m][n], 0, 0, 0);
    __syncthreads();
  }

  sS[srA][t & 7]      = sumA;
  sS[srA + 32][t & 7] = sumB;
  __syncthreads();
  if (t < 64){
    float s = 0.f;
    #pragma unroll
    for (int e = 0; e < 8; ++e) s += sS[t][e];
    sInv[t] = 1.0f / s;
  }
  __syncthreads();

  #pragma unroll
  for (int m = 0; m < 4; ++m){
    #pragma unroll
    for (int r = 0; r < 4; ++r){
      const int lr = m*16 + lh*4 + r;
      const int gi = (lr < 32) ? (i0 + lr) : (i0 + lr - 32 + HALF_ROWS);
      const float inv = sInv[lr];
      #pragma unroll
      for (int n = 0; n < 4; ++n)
        zq[(size_t)gi*DIM + w*64 + n*16 + ll] = acc[m][n][r] * inv;
    }
  }
}

// ---------------- launch ----------------------------------------------------
extern "C" void kernel_launch(void* const* d_in, const int* in_sizes, int n_in,
                              void* d_out, int out_size, void* d_ws, size_t ws_size,
                              hipStream_t stream)
{
  (void)in_sizes; (void)n_in; (void)out_size;
  const float* z    = (const float*)d_in[0];
  const float* cp   = (const float*)d_in[1];
  const float* lpq  = (const float*)d_in[2];
  const float* book = (const float*)d_in[3];
  const float* mu   = (const float*)d_in[4];
  const int*   temp = (const int*)d_in[5];
  // d_in[6] = is_train, unused by the reference computation

  float* out = (float*)d_out;
  float* zq  = out;
  float* pqo = out + OFF_PQ;
  float* lg  = out + OFF_LG;
  float* mm  = out + OFF_MM;

  float* ws    = (float*)d_ws;
  float* bn    = ws;
  float* rn    = ws + WS_RN;
  float* wpq   = ws + WS_PQ;
  u16*   bookF = (u16*)(ws + WS_BF);

  if (ws_size >= WS_A_BYTES){
    // ---- tier A: fused pipeline (bookQ in ws) ----
    u16* bookQ = (u16*)(ws + WS_BQ);
    hipLaunchKernelGGL(k_prep,  dim3(BOOKN), dim3(256), 0, stream,
                       book, lpq, bn, wpq, pqo, (unsigned int*)nullptr);
    hipLaunchKernelGGL(k_bookf, dim3(256), dim3(256), 0, stream,
                       book, bookF, (u16*)nullptr, bookQ);
    hipLaunchKernelGGL(k_mix,   dim3(NPTS, 2), dim3(256), 0, stream,
                       z, cp, mu, (u16*)nullptr, mm, rn);
    hipLaunchKernelGGL(k_fused, dim3(HALF_ROWS/32), dim3(256), 0, stream,
                       z, mm, rn, bn, wpq, bookQ, bookF, temp, lg, zq);
  } else {
    // ---- tier B/C: round-5-proven pipeline ----
    u16* zpBF  = (u16*)zq;
    u16* bookR = (u16*)zq + (size_t)NROWS*DIM;
    unsigned int* wsMax = (ws_size >= WS_FUSED_BYTES)
                        ? (unsigned int*)(ws + WS_MX) : nullptr;
    hipLaunchKernelGGL(k_prep,   dim3(BOOKN), dim3(256), 0, stream,
                       book, lpq, bn, wpq, pqo, wsMax);
    hipLaunchKernelGGL(k_bookf,  dim3(256), dim3(256), 0, stream,
                       book, bookF, bookR, (u16*)nullptr);
    hipLaunchKernelGGL(k_mix,    dim3(NPTS, 2), dim3(256), 0, stream,
                       z, cp, mu, zpBF, mm, rn);
    hipLaunchKernelGGL(k_logits, dim3(BOOKN/128, NROWS/128), dim3(256), 0, stream,
                       zpBF, bookR, rn, bn, wpq, lg, wsMax);
    hipLaunchKernelGGL(k_zq,     dim3(HALF_ROWS/32), dim3(256), 0, stream,
                       lg, bookF, temp, wsMax, zq);
  }
}